// Round 12
// baseline (208.701 us; speedup 1.0000x reference)
//
#include <hip/hip_runtime.h>
#include <hip/hip_bf16.h>

#define B_ 4
#define S_ 2048
#define D_ 1024
#define MTOT (B_ * S_)

typedef __attribute__((ext_vector_type(8))) short bf16x8;
typedef __attribute__((ext_vector_type(4))) float f32x4;

__device__ __forceinline__ unsigned short f2bf(float f) {
  union { float f; unsigned int u; } v; v.f = f;
  unsigned int r = v.u + 0x7FFFu + ((v.u >> 16) & 1u);
  return (unsigned short)(r >> 16);
}
__device__ __forceinline__ float bf2f(unsigned short u) {
  union { unsigned int u; float f; } v; v.u = ((unsigned int)u) << 16;
  return v.f;
}

// ------------- fused fp32->bf16 convert: X -> Xb, {Wq,Wk,Wv} -> Wqkv -------------
__global__ __launch_bounds__(256) void cvt_all(const float* __restrict__ X,
                                               const float* __restrict__ Wq,
                                               const float* __restrict__ Wk,
                                               const float* __restrict__ Wv,
                                               unsigned short* __restrict__ Xb,
                                               unsigned short* __restrict__ Wqkv) {
  long i = (long)blockIdx.x * 256 + threadIdx.x;  // float4 index
  const float* src;
  unsigned short* dst;
  long off;
  if (i < 2097152L) {  // X: 8M elems
    src = X; dst = Xb; off = i;
  } else {
    long j = i - 2097152L;
    int w = (int)(j >> 18);          // 262144 float4 per W
    off = j & 262143L;
    src = (w == 0) ? Wq : (w == 1) ? Wk : Wv;
    dst = Wqkv + (long)w * 1048576L;
  }
  float4 v = ((const float4*)src)[off];
  ushort4 o;
  o.x = f2bf(v.x); o.y = f2bf(v.y); o.z = f2bf(v.z); o.w = f2bf(v.w);
  ((ushort4*)dst)[off] = o;
}

// ---- row norms: rq[row]=rsqrt(|Q_row|^2), rk[row]=rsqrt(|K_row|^2) (bf16 in) ----
__global__ __launch_bounds__(256) void norms_bf16(const unsigned short* __restrict__ QKraw,
                                                  float* __restrict__ rq,
                                                  float* __restrict__ rk) {
  int row = blockIdx.x;
  int half = blockIdx.y;
  int tid = threadIdx.x;
  const unsigned short* src = QKraw + (long)half * MTOT * D_ + (long)row * D_;
  ushort4 u = *(const ushort4*)(src + tid * 4);
  float x0 = bf2f(u.x), x1 = bf2f(u.y), x2 = bf2f(u.z), x3 = bf2f(u.w);
  float ss = x0 * x0 + x1 * x1 + x2 * x2 + x3 * x3;
#pragma unroll
  for (int o = 1; o < 64; o <<= 1) ss += __shfl_xor(ss, o);
  __shared__ float wsum[4];
  if ((tid & 63) == 0) wsum[tid >> 6] = ss;
  __syncthreads();
  if (tid == 0) {
    float r = rsqrtf(wsum[0] + wsum[1] + wsum[2] + wsum[3]);
    (half ? rk : rq)[row] = r;
  }
}

// ========= 128xBN MFMA GEMM, BK=128, single-buffer m97 structure =========
// C[M,N] = A[M,K] @ B[N,K]^T. 256 threads (4 waves 2x2). NT = K/128 iters,
// 2 barriers/iter -> HALF the stage drains of BK=64 (R7's proven lever, applied
// again). Row = 256B = 16 chunks of 16B; XOR swizzle chunk ^= (row&7) on global
// staging source + ds_read offset (within-row permutation: coalescing intact,
// read banks conflict-free). LDS: A 32KB + B 32/16KB (single buffer).
// EPI: 0 fp32 out; 1 fused-QKV (Q,K raw bf16 + V scattered to [b][d][s]);
//      2 bf16 score out: v * rq[row] * rk[col] * attention mask (direct global).

#define GLDS16(g, l)                                                                   \
  __builtin_amdgcn_global_load_lds((const __attribute__((address_space(1))) void*)(g), \
                                   (__attribute__((address_space(3))) void*)(l), 16, 0, 0)

template <int EPI, int BN>
__global__ __launch_bounds__(256, 2) void gemm_k128(const unsigned short* __restrict__ A,
                                                    const unsigned short* __restrict__ B,
                                                    void* __restrict__ Cv, int N, int K,
                                                    long strideA, long strideB, long strideC,
                                                    const int* __restrict__ masks,
                                                    const float* __restrict__ rqp,
                                                    const float* __restrict__ rkp) {
  constexpr int NBF = BN / 32;       // B-frags per wave per k-step (128->4, 64->2)
  constexpr int NBJ = BN / 16;       // B staging loads per thread (8 or 4)
  __shared__ __align__(16) short lA[128 * 128];  // 32KB: 128 rows x 256B
  __shared__ __align__(16) short lB[BN * 128];   // 32/16KB

  const int z = blockIdx.z;
  const unsigned short* Ab = A + (long)z * strideA;
  const unsigned short* Bb = B + (long)z * strideB;
  const int t = threadIdx.x;
  const int lane = t & 63, w = t >> 6;
  const int wr = w >> 1, wc = w & 1;
  const int fr = lane & 15, fq = lane >> 4;
  const int brow = blockIdx.x * 128, bcol = blockIdx.y * BN;
  const long K2 = (long)K * 2;

  // staging: thread t -> LDS chunk t (+256j), i.e. row (t>>4)+16j, slot t&15.
  // source slot pre-XOR'd by row&7 (((t>>4)+16j)&7 == (t>>4)&7, one offset serves all j)
  const int srow = t >> 4;
  const int sslot = ((t & 15) ^ (srow & 7)) << 4;
  const char* gAs = (const char*)Ab + (long)(brow + srow) * K2 + sslot;
  const char* gBs = (const char*)Bb + (long)(bcol + srow) * K2 + sslot;
  const long jstr = (long)16 * K2;  // +16 rows
  char* lAd = (char*)&lA[0] + t * 16;
  char* lBd = (char*)&lB[0] + t * 16;

#define STAGE()                                               \
  do {                                                        \
    _Pragma("unroll") for (int j = 0; j < 8; ++j)             \
        GLDS16(gAs + j * jstr, lAd + j * 4096);               \
    _Pragma("unroll") for (int j = 0; j < NBJ; ++j)           \
        GLDS16(gBs + j * jstr, lBd + j * 4096);               \
    gAs += 256;                                               \
    gBs += 256;                                               \
  } while (0)

  f32x4 acc[4][NBF];
#pragma unroll
  for (int m = 0; m < 4; m++)
#pragma unroll
    for (int n = 0; n < NBF; n++) acc[m][n] = (f32x4){0.f, 0.f, 0.f, 0.f};

  // ds_read byte offsets: row r at r*256, k-chunk (ks*4+fq) XOR'd by (fr&7)
  int cb[4];
#pragma unroll
  for (int ks = 0; ks < 4; ++ks) cb[ks] = (((ks << 2) | fq) ^ (fr & 7)) << 4;
  const int arow0 = (wr * 64 + fr) << 8;          // *256B
  const int brow0 = (wc * (BN / 2) + fr) << 8;

  const int NT = K / 128;
  for (int kt = 0; kt < NT; ++kt) {
    STAGE();
    __syncthreads();  // implicit vmcnt(0)+lgkmcnt(0): tile landed, prior reads done
#pragma unroll
    for (int ks = 0; ks < 4; ++ks) {
      bf16x8 af[4], bv[NBF];
#pragma unroll
      for (int m = 0; m < 4; m++)
        af[m] = *(const bf16x8*)((const char*)&lA[0] + arow0 + (m << 12) + cb[ks]);
#pragma unroll
      for (int n = 0; n < NBF; n++)
        bv[n] = *(const bf16x8*)((const char*)&lB[0] + brow0 + (n << 12) + cb[ks]);
#pragma unroll
      for (int m = 0; m < 4; m++)
#pragma unroll
        for (int n = 0; n < NBF; n++)
          acc[m][n] = __builtin_amdgcn_mfma_f32_16x16x32_bf16(af[m], bv[n], acc[m][n], 0, 0, 0);
    }
    if (kt + 1 < NT) __syncthreads();  // guard buffer reuse
  }
#undef STAGE

  long cbase = (long)z * strideC;
#pragma unroll
  for (int m = 0; m < 4; m++) {
#pragma unroll
    for (int n = 0; n < NBF; n++) {
#pragma unroll
      for (int r = 0; r < 4; r++) {
        int grow = brow + wr * 64 + m * 16 + fq * 4 + r;
        int gcol = bcol + wc * (BN / 2) + n * 16 + fr;
        float v = acc[m][n][r];
        if constexpr (EPI == 0) {
          ((float*)Cv)[cbase + (long)grow * N + gcol] = v;
        } else if constexpr (EPI == 1) {
          // fused QKV: seg 0 -> Qraw, 1 -> Kraw, 2 -> Vt[b][d][s]
          unsigned short* base = (unsigned short*)Cv;
          int seg = gcol >> 10, c = gcol & 1023;
          if (seg == 0) {
            base[(long)grow * D_ + c] = f2bf(v);
          } else if (seg == 1) {
            base[(long)MTOT * D_ + (long)grow * D_ + c] = f2bf(v);
          } else {
            int b = grow >> 11, s = grow & (S_ - 1);
            base[(long)2 * MTOT * D_ + (long)b * D_ * S_ + (long)c * S_ + s] = f2bf(v);
          }
        } else {
          // cosine-normalized score: v * rq[row]*rk[col]; keep where (k>q) OR pad
          bool keep = (gcol > grow) || (masks[(long)z * S_ + gcol] == 0);
          float sv = v * rqp[(long)z * S_ + grow] * rkp[(long)z * S_ + gcol];
          ((unsigned short*)Cv)[cbase + (long)grow * N + gcol] = keep ? f2bf(sv) : (unsigned short)0;
        }
      }
    }
  }
}

extern "C" void kernel_launch(void* const* d_in, const int* in_sizes, int n_in, void* d_out,
                              int out_size, void* d_ws, size_t ws_size, hipStream_t stream) {
  (void)in_sizes; (void)n_in; (void)out_size; (void)ws_size;
  const float* X = (const float*)d_in[0];
  const int* masks = (const int*)d_in[1];
  const float* Wq = (const float*)d_in[2];
  const float* Wk = (const float*)d_in[3];
  const float* Wv = (const float*)d_in[4];
  float* out = (float*)d_out;

  char* ws = (char*)d_ws;
  unsigned short* Xb = (unsigned short*)ws;     ws += (long)MTOT * D_ * 2;
  unsigned short* Wqkv = (unsigned short*)ws;   ws += (long)3 * D_ * D_ * 2;
  unsigned short* QKVraw = (unsigned short*)ws; ws += (long)3 * MTOT * D_ * 2;  // Qraw|Kraw|Vt
  float* rq = (float*)ws;                       ws += (long)MTOT * 4;
  float* rk = (float*)ws;                       ws += (long)MTOT * 4;
  unsigned short* Sm = (unsigned short*)ws;     ws += (long)B_ * S_ * S_ * 2;
  unsigned short* Qraw = QKVraw;
  unsigned short* Kraw = QKVraw + (long)MTOT * D_;
  unsigned short* Vt = QKVraw + (long)2 * MTOT * D_;

  // fused converts: X + {Wq,Wk,Wv} -> Xb, Wqkv ([3][1024][1024])
  cvt_all<<<11264, 256, 0, stream>>>(X, Wq, Wk, Wv, Xb, Wqkv);

  // fused [Q|K|V] = X @ Wqkv^T  (M=8192, N=3072, K=1024; V pre-transposed)
  gemm_k128<1, 128><<<dim3(MTOT / 128, 3 * D_ / 128, 1), 256, 0, stream>>>(
      Xb, Wqkv, QKVraw, 3 * D_, D_, 0, 0, 0, nullptr, nullptr, nullptr);
  // row norms of raw Q and K (rsqrt of sum-of-squares)
  norms_bf16<<<dim3(MTOT, 2), 256, 0, stream>>>(QKVraw, rq, rk);
  // S[b] = diag(rq) (Q K^T) diag(rk) * mask  (bf16; grid 16x16x4)
  gemm_k128<2, 128><<<dim3(S_ / 128, S_ / 128, B_), 256, 0, stream>>>(
      Qraw, Kraw, Sm, S_, D_, (long)S_ * D_, (long)S_ * D_, (long)S_ * S_, masks, rq, rk);
  // out[b] = S[b] @ V[b]  (A=Sm [S][S], B=Vt [D][S], fp32; BN=64 -> grid 16x16x4)
  gemm_k128<0, 64><<<dim3(S_ / 128, D_ / 64, B_), 256, 0, stream>>>(
      Sm, Vt, out, D_, S_, (long)S_ * S_, (long)D_ * S_, (long)S_ * D_, nullptr, nullptr, nullptr);
}

// Round 13
// 164.216 us; speedup vs baseline: 1.2709x; 1.2709x over previous
//
#include <hip/hip_runtime.h>
#include <hip/hip_bf16.h>

#define B_ 4
#define S_ 2048
#define D_ 1024
#define MTOT (B_ * S_)

typedef __attribute__((ext_vector_type(8))) short bf16x8;
typedef __attribute__((ext_vector_type(4))) float f32x4;

__device__ __forceinline__ unsigned short f2bf(float f) {
  union { float f; unsigned int u; } v; v.f = f;
  unsigned int r = v.u + 0x7FFFu + ((v.u >> 16) & 1u);
  return (unsigned short)(r >> 16);
}
__device__ __forceinline__ float bf2f(unsigned short u) {
  union { unsigned int u; float f; } v; v.u = ((unsigned int)u) << 16;
  return v.f;
}

// ------------- fused fp32->bf16 convert: X -> Xb, {Wq,Wk,Wv} -> Wqkv -------------
__global__ __launch_bounds__(256) void cvt_all(const float* __restrict__ X,
                                               const float* __restrict__ Wq,
                                               const float* __restrict__ Wk,
                                               const float* __restrict__ Wv,
                                               unsigned short* __restrict__ Xb,
                                               unsigned short* __restrict__ Wqkv) {
  long i = (long)blockIdx.x * 256 + threadIdx.x;  // float4 index
  const float* src;
  unsigned short* dst;
  long off;
  if (i < 2097152L) {  // X: 8M elems
    src = X; dst = Xb; off = i;
  } else {
    long j = i - 2097152L;
    int w = (int)(j >> 18);          // 262144 float4 per W
    off = j & 262143L;
    src = (w == 0) ? Wq : (w == 1) ? Wk : Wv;
    dst = Wqkv + (long)w * 1048576L;
  }
  float4 v = ((const float4*)src)[off];
  ushort4 o;
  o.x = f2bf(v.x); o.y = f2bf(v.y); o.z = f2bf(v.z); o.w = f2bf(v.w);
  ((ushort4*)dst)[off] = o;
}

// ---- row norms: rq[row]=rsqrt(|Q_row|^2), rk[row]=rsqrt(|K_row|^2) (bf16 in) ----
__global__ __launch_bounds__(256) void norms_bf16(const unsigned short* __restrict__ QKraw,
                                                  float* __restrict__ rq,
                                                  float* __restrict__ rk) {
  int row = blockIdx.x;
  int half = blockIdx.y;
  int tid = threadIdx.x;
  const unsigned short* src = QKraw + (long)half * MTOT * D_ + (long)row * D_;
  ushort4 u = *(const ushort4*)(src + tid * 4);
  float x0 = bf2f(u.x), x1 = bf2f(u.y), x2 = bf2f(u.z), x3 = bf2f(u.w);
  float ss = x0 * x0 + x1 * x1 + x2 * x2 + x3 * x3;
#pragma unroll
  for (int o = 1; o < 64; o <<= 1) ss += __shfl_xor(ss, o);
  __shared__ float wsum[4];
  if ((tid & 63) == 0) wsum[tid >> 6] = ss;
  __syncthreads();
  if (tid == 0) {
    float r = rsqrtf(wsum[0] + wsum[1] + wsum[2] + wsum[3]);
    (half ? rk : rq)[row] = r;
  }
}

// ========= 128xBN MFMA GEMM, BK=64, single-buffer m97 structure =========
// C[M,N] = A[M,K] @ B[N,K]^T. 256 threads (4 waves 2x2). NT = K/64 iters,
// 2 barriers/iter. XOR swizzle within each 128B row (chunk ^= row&7),
// applied to global staging source and ds_read offset (coalescing preserved).
// EPI: 0 fp32 out; 1 fused-QKV (Q,K raw bf16 + V scattered to [b][d][s]);
//      2 bf16 score out: v * rq[row] * rk[col], multiplied by attention mask.
// Measured (R9/R11): total 164.3-164.5 us, QKV ~77 us @ 670 TF, conflicts 0.
// Structural alternatives all measured WORSE on this problem: 8-phase ports
// (R3 507TF, R4 437TF), triple-buf counted-vmcnt (R5 380TF), slot-major (R6),
// explicit dbuf (R10), BK=128 (R12). Wins were fusion + factored norms + BK64.

#define GLDS16(g, l)                                                                   \
  __builtin_amdgcn_global_load_lds((const __attribute__((address_space(1))) void*)(g), \
                                   (__attribute__((address_space(3))) void*)(l), 16, 0, 0)

template <int EPI, int BN>
__global__ __launch_bounds__(256, 4) void gemm_k64(const unsigned short* __restrict__ A,
                                                   const unsigned short* __restrict__ B,
                                                   void* __restrict__ Cv, int N, int K,
                                                   long strideA, long strideB, long strideC,
                                                   const int* __restrict__ masks,
                                                   const float* __restrict__ rqp,
                                                   const float* __restrict__ rkp) {
  constexpr int NBF = BN / 32;  // B-frags per wave per k-step (128->4, 64->2)
  __shared__ __align__(16) short lA[128 * 64];  // 16KB, rows of 128B
  __shared__ __align__(16) short lB[BN * 64];   // 16/8KB
  __shared__ float srq[128], srk[128];
  __shared__ int smask[128];

  const int z = blockIdx.z;
  const unsigned short* Ab = A + (long)z * strideA;
  const unsigned short* Bb = B + (long)z * strideB;
  const int t = threadIdx.x;
  const int lane = t & 63, w = t >> 6;
  const int wr = w >> 1, wc = w & 1;
  const int fr = lane & 15, fq = lane >> 4;
  const int brow = blockIdx.x * 128, bcol = blockIdx.y * BN;
  const long K2 = (long)K * 2;

  if constexpr (EPI == 2) {
    if (t < 128) {
      smask[t] = masks[(long)z * S_ + bcol + t];
      srk[t] = rkp[(long)z * S_ + bcol + t];   // rq/rk are GLOBAL-row indexed
    } else {
      srq[t - 128] = rqp[(long)z * S_ + brow + (t - 128)];
    }
  }

  // staging: thread t -> LDS chunk t (+256j), i.e. row t>>3 (+32j), 16B-slot t&7.
  const int srow = t >> 3;
  const int sslot = ((t & 7) ^ (srow & 7)) << 4;
  const char* gAs = (const char*)Ab + (long)(brow + srow) * K2 + sslot;
  const char* gBs = (const char*)Bb + (long)(bcol + srow) * K2 + sslot;
  const long jstr = (long)32 * K2;  // +32 rows
  char* lAd = (char*)&lA[0] + t * 16;
  char* lBd = (char*)&lB[0] + t * 16;

#define STAGE()                                               \
  do {                                                        \
    _Pragma("unroll") for (int j = 0; j < 4; ++j)             \
        GLDS16(gAs + j * jstr, lAd + j * 4096);               \
    _Pragma("unroll") for (int j = 0; j < NBF; ++j)           \
        GLDS16(gBs + j * jstr, lBd + j * 4096);               \
    gAs += 128;                                               \
    gBs += 128;                                               \
  } while (0)

  f32x4 acc[4][NBF];
#pragma unroll
  for (int m = 0; m < 4; m++)
#pragma unroll
    for (int n = 0; n < NBF; n++) acc[m][n] = (f32x4){0.f, 0.f, 0.f, 0.f};

  // ds_read byte offsets: row r at r*128, k-chunk (ks*4+fq) XOR'd by (fr&7)
  int cbyte[2];
#pragma unroll
  for (int ks = 0; ks < 2; ++ks) cbyte[ks] = (((ks << 2) | fq) ^ (fr & 7)) << 4;
  const int arow0 = (wr * 64 + fr) << 7;          // *128B
  const int brow0 = (wc * (BN / 2) + fr) << 7;

  const int NT = K / 64;
  for (int kt = 0; kt < NT; ++kt) {
    STAGE();
    __syncthreads();  // implicit vmcnt(0)+lgkmcnt(0): tile landed, prior reads done
#pragma unroll
    for (int ks = 0; ks < 2; ++ks) {
      bf16x8 af[4], bv[NBF];
#pragma unroll
      for (int m = 0; m < 4; m++)
        af[m] = *(const bf16x8*)((const char*)&lA[0] + arow0 + (m << 11) + cbyte[ks]);
#pragma unroll
      for (int n = 0; n < NBF; n++)
        bv[n] = *(const bf16x8*)((const char*)&lB[0] + brow0 + (n << 11) + cbyte[ks]);
#pragma unroll
      for (int m = 0; m < 4; m++)
#pragma unroll
        for (int n = 0; n < NBF; n++)
          acc[m][n] = __builtin_amdgcn_mfma_f32_16x16x32_bf16(af[m], bv[n], acc[m][n], 0, 0, 0);
    }
    if (kt + 1 < NT) __syncthreads();  // guard buffer reuse
  }
#undef STAGE

  long cbase = (long)z * strideC;
#pragma unroll
  for (int m = 0; m < 4; m++) {
#pragma unroll
    for (int n = 0; n < NBF; n++) {
#pragma unroll
      for (int r = 0; r < 4; r++) {
        int lr = wr * 64 + m * 16 + fq * 4 + r;
        int lc = wc * (BN / 2) + n * 16 + fr;
        int grow = brow + lr;
        int gcol = bcol + lc;
        float v = acc[m][n][r];
        if constexpr (EPI == 0) {
          ((float*)Cv)[cbase + (long)grow * N + gcol] = v;
        } else if constexpr (EPI == 1) {
          // fused QKV: seg 0 -> Qraw, 1 -> Kraw, 2 -> Vt[b][d][s]
          unsigned short* base = (unsigned short*)Cv;
          int seg = gcol >> 10, c = gcol & 1023;
          if (seg == 0) {
            base[(long)grow * D_ + c] = f2bf(v);
          } else if (seg == 1) {
            base[(long)MTOT * D_ + (long)grow * D_ + c] = f2bf(v);
          } else {
            int b = grow >> 11, s = grow & (S_ - 1);
            base[(long)2 * MTOT * D_ + (long)b * D_ * S_ + (long)c * S_ + s] = f2bf(v);
          }
        } else {
          // cosine-normalized score: v * rq[row]*rk[col]; keep where (k>q) OR pad
          bool keep = (gcol > grow) || (smask[lc] == 0);
          float sv = v * srq[lr] * srk[lc];
          ((unsigned short*)Cv)[cbase + (long)grow * N + gcol] = keep ? f2bf(sv) : (unsigned short)0;
        }
      }
    }
  }
}

extern "C" void kernel_launch(void* const* d_in, const int* in_sizes, int n_in, void* d_out,
                              int out_size, void* d_ws, size_t ws_size, hipStream_t stream) {
  (void)in_sizes; (void)n_in; (void)out_size; (void)ws_size;
  const float* X = (const float*)d_in[0];
  const int* masks = (const int*)d_in[1];
  const float* Wq = (const float*)d_in[2];
  const float* Wk = (const float*)d_in[3];
  const float* Wv = (const float*)d_in[4];
  float* out = (float*)d_out;

  char* ws = (char*)d_ws;
  unsigned short* Xb = (unsigned short*)ws;     ws += (long)MTOT * D_ * 2;
  unsigned short* Wqkv = (unsigned short*)ws;   ws += (long)3 * D_ * D_ * 2;
  unsigned short* QKVraw = (unsigned short*)ws; ws += (long)3 * MTOT * D_ * 2;  // Qraw|Kraw|Vt
  float* rq = (float*)ws;                       ws += (long)MTOT * 4;
  float* rk = (float*)ws;                       ws += (long)MTOT * 4;
  unsigned short* Sm = (unsigned short*)ws;     ws += (long)B_ * S_ * S_ * 2;
  unsigned short* Qraw = QKVraw;
  unsigned short* Kraw = QKVraw + (long)MTOT * D_;
  unsigned short* Vt = QKVraw + (long)2 * MTOT * D_;

  // fused converts: X + {Wq,Wk,Wv} -> Xb, Wqkv ([3][1024][1024])
  cvt_all<<<11264, 256, 0, stream>>>(X, Wq, Wk, Wv, Xb, Wqkv);

  // fused [Q|K|V] = X @ Wqkv^T  (M=8192, N=3072, K=1024; V pre-transposed)
  gemm_k64<1, 128><<<dim3(MTOT / 128, 3 * D_ / 128, 1), 256, 0, stream>>>(
      Xb, Wqkv, QKVraw, 3 * D_, D_, 0, 0, 0, nullptr, nullptr, nullptr);
  // row norms of raw Q and K (rsqrt of sum-of-squares)
  norms_bf16<<<dim3(MTOT, 2), 256, 0, stream>>>(QKVraw, rq, rk);
  // S[b] = diag(rq) (Q K^T) diag(rk) * mask  (bf16; grid 16x16x4)
  gemm_k64<2, 128><<<dim3(S_ / 128, S_ / 128, B_), 256, 0, stream>>>(
      Qraw, Kraw, Sm, S_, D_, (long)S_ * D_, (long)S_ * D_, (long)S_ * S_, masks, rq, rk);
  // out[b] = S[b] @ V[b]  (A=Sm [S][S], B=Vt [D][S], fp32; BN=64 -> grid 16x16x4)
  gemm_k64<0, 64><<<dim3(S_ / 128, D_ / 64, B_), 256, 0, stream>>>(
      Sm, Vt, out, D_, S_, (long)S_ * S_, (long)D_ * S_, (long)S_ * D_, nullptr, nullptr, nullptr);
}